// Round 1
// baseline (650.755 us; speedup 1.0000x reference)
//
#include <hip/hip_runtime.h>

#define NN 8192
constexpr float EPS = 1e-4f;

// ---------------------------------------------------------------------------
// Sinkhorn in factored form: out_ij = (A_ij + EPS) * r_i * c_j, where
//   even iter k: r_i = 1 / sum_j (A_ij+EPS)*c_j
//   odd  iter k: c_j = 1 / sum_i (A_ij+EPS)*r_i
// 10 iterations = 5 (row, col) pairs, then one finalize pass.
// ---------------------------------------------------------------------------

__global__ __launch_bounds__(256) void k_init_ones(float* __restrict__ v) {
    v[blockIdx.x * 256 + threadIdx.x] = 1.0f;
}

// r[row] = 1 / sum_j (A[row][j]+EPS)*c[j]; one block per row.
__global__ __launch_bounds__(256) void k_row_pass(const float* __restrict__ A,
                                                  const float* __restrict__ c,
                                                  float* __restrict__ r) {
    const int row = blockIdx.x;
    const float4* A4 = reinterpret_cast<const float4*>(A + (size_t)row * NN);
    const float4* c4 = reinterpret_cast<const float4*>(c);
    float sum = 0.0f;
    #pragma unroll
    for (int k = threadIdx.x; k < NN / 4; k += 256) {  // 8 iterations
        float4 a = A4[k];
        float4 w = c4[k];
        sum += (a.x + EPS) * w.x;
        sum += (a.y + EPS) * w.y;
        sum += (a.z + EPS) * w.z;
        sum += (a.w + EPS) * w.w;
    }
    #pragma unroll
    for (int off = 32; off > 0; off >>= 1) sum += __shfl_down(sum, off);
    __shared__ float smem[4];
    const int lane = threadIdx.x & 63;
    const int wid  = threadIdx.x >> 6;
    if (lane == 0) smem[wid] = sum;
    __syncthreads();
    if (threadIdx.x == 0) {
        r[row] = 1.0f / (smem[0] + smem[1] + smem[2] + smem[3]);
    }
}

// partial[slice][j] = sum over this slice's rows of (A[i][j]+EPS)*r[i]
// Each thread owns 4 consecutive columns (one float4); coalesced across wave.
__global__ __launch_bounds__(256) void k_col_pass(const float* __restrict__ A,
                                                  const float* __restrict__ r,
                                                  float* __restrict__ partial,
                                                  int rows_per) {
    const int j4 = blockIdx.x * 256 + threadIdx.x;   // float4 column index
    const int i0 = blockIdx.y * rows_per;
    const float4* A4 = reinterpret_cast<const float4*>(A);
    float4 acc = make_float4(0.f, 0.f, 0.f, 0.f);
    #pragma unroll 4
    for (int i = i0; i < i0 + rows_per; ++i) {
        const float ri = r[i];                       // wave-uniform -> scalar load
        float4 a = A4[(size_t)i * (NN / 4) + j4];
        acc.x += (a.x + EPS) * ri;
        acc.y += (a.y + EPS) * ri;
        acc.z += (a.z + EPS) * ri;
        acc.w += (a.w + EPS) * ri;
    }
    float4* P4 = reinterpret_cast<float4*>(partial);
    P4[(size_t)blockIdx.y * (NN / 4) + j4] = acc;
}

// c[j] = 1 / sum_s partial[s][j]   (fixed-order, deterministic)
__global__ __launch_bounds__(256) void k_col_reduce(const float* __restrict__ partial,
                                                    float* __restrict__ c, int S) {
    const int j = blockIdx.x * 256 + threadIdx.x;
    float t = 0.0f;
    for (int s = 0; s < S; ++s) t += partial[(size_t)s * NN + j];
    c[j] = 1.0f / t;
}

// out_ij = (A_ij + EPS) * r_i * c_j, float4 grid-stride
__global__ __launch_bounds__(256) void k_finalize(const float* __restrict__ A,
                                                  const float* __restrict__ r,
                                                  const float* __restrict__ c,
                                                  float* __restrict__ out) {
    const float4* A4 = reinterpret_cast<const float4*>(A);
    const float4* c4 = reinterpret_cast<const float4*>(c);
    float4* O4 = reinterpret_cast<float4*>(out);
    const size_t total  = (size_t)NN * NN / 4;       // 16M float4
    const size_t stride = (size_t)gridDim.x * 256;
    for (size_t k = (size_t)blockIdx.x * 256 + threadIdx.x; k < total; k += stride) {
        const int row = (int)(k >> 11);              // NN/4 == 2048
        const int jc  = (int)(k & 2047);
        const float s = r[row];
        float4 a = A4[k];
        float4 w = c4[jc];
        float4 o;
        o.x = (a.x + EPS) * s * w.x;
        o.y = (a.y + EPS) * s * w.y;
        o.z = (a.z + EPS) * s * w.z;
        o.w = (a.w + EPS) * s * w.w;
        O4[k] = o;
    }
}

extern "C" void kernel_launch(void* const* d_in, const int* in_sizes, int n_in,
                              void* d_out, int out_size, void* d_ws, size_t ws_size,
                              hipStream_t stream) {
    const float* A = (const float*)d_in[0];
    float* out = (float*)d_out;

    // Workspace layout: r[NN] | c[NN] | partial[S*NN]
    float* r       = (float*)d_ws;
    float* c       = r + NN;
    float* partial = c + NN;

    int S = 64;  // row slices for the column pass (power of two dividing NN)
    while (S > 1 && ((size_t)S * NN + 2 * NN) * sizeof(float) > ws_size) S >>= 1;
    const int rows_per = NN / S;

    k_init_ones<<<NN / 256, 256, 0, stream>>>(c);
    for (int it = 0; it < 5; ++it) {
        k_row_pass<<<NN, 256, 0, stream>>>(A, c, r);
        k_col_pass<<<dim3(NN / 1024, S), 256, 0, stream>>>(A, r, partial, rows_per);
        k_col_reduce<<<NN / 256, 256, 0, stream>>>(partial, c, S);
    }
    k_finalize<<<2048, 256, 0, stream>>>(A, r, c, out);
}

// Round 2
// 469.017 us; speedup vs baseline: 1.3875x; 1.3875x over previous
//
#include <hip/hip_runtime.h>

#define NN 8192
#define NF4 (NN / 4)      // 2048 float4 per row
#define THREADS 256
#define GROUPS 8          // 8 float4-groups/thread * 4 * 256 threads = 8192 cols
constexpr float EPS = 1e-4f;

// ---------------------------------------------------------------------------
// Sinkhorn in factored form: out_ij = (A_ij+EPS) * r_i * c_j
//   pair pass p: r_i = 1/((A+e)_i . c) ; partial col sums += r_i*(A+e)_ij
// Each pair reads A ONCE (row stripe held in registers between the row-dot
// and the column accumulation). 5 pairs + 1 finalize = 6 passes over A.
// ---------------------------------------------------------------------------

// Fused (row-normalize, col-accumulate) pass. One block per row stripe.
// Thread t owns float4 columns {g*256+t : g in 0..7} (coalesced).
template <bool FIRST, bool REV>
__global__ __launch_bounds__(THREADS) void k_pair(const float* __restrict__ A,
                                                  const float* __restrict__ c,
                                                  float* __restrict__ r_out,
                                                  float* __restrict__ partial,
                                                  int rows_per) {
    const int t = threadIdx.x;
    const float4* A4 = reinterpret_cast<const float4*>(A);
    const float4* c4 = reinterpret_cast<const float4*>(c);

    float4 creg[GROUPS];
    if (FIRST) {
        #pragma unroll
        for (int g = 0; g < GROUPS; ++g) creg[g] = make_float4(1.f, 1.f, 1.f, 1.f);
    } else {
        #pragma unroll
        for (int g = 0; g < GROUPS; ++g) creg[g] = c4[g * THREADS + t];
    }
    float4 acc[GROUPS];
    #pragma unroll
    for (int g = 0; g < GROUPS; ++g) acc[g] = make_float4(0.f, 0.f, 0.f, 0.f);

    __shared__ float smem[2][4];
    const int lane = t & 63, wid = t >> 6;
    const int base = REV ? (NN - (blockIdx.x + 1) * rows_per)
                         : blockIdx.x * rows_per;

    for (int rr = 0; rr < rows_per; ++rr) {
        const int row = base + rr;
        float4 ae[GROUPS];
        #pragma unroll
        for (int g = 0; g < GROUPS; ++g) {
            float4 a = A4[(size_t)row * NF4 + g * THREADS + t];
            ae[g] = make_float4(a.x + EPS, a.y + EPS, a.z + EPS, a.w + EPS);
        }
        float p = 0.f;
        #pragma unroll
        for (int g = 0; g < GROUPS; ++g) {
            p += ae[g].x * creg[g].x + ae[g].y * creg[g].y
               + ae[g].z * creg[g].z + ae[g].w * creg[g].w;
        }
        #pragma unroll
        for (int off = 32; off > 0; off >>= 1) p += __shfl_down(p, off);
        if (lane == 0) smem[rr & 1][wid] = p;
        __syncthreads();
        const float ri = 1.0f / (smem[rr & 1][0] + smem[rr & 1][1] +
                                 smem[rr & 1][2] + smem[rr & 1][3]);
        if (t == 0) r_out[row] = ri;
        #pragma unroll
        for (int g = 0; g < GROUPS; ++g) {
            acc[g].x += ri * ae[g].x;
            acc[g].y += ri * ae[g].y;
            acc[g].z += ri * ae[g].z;
            acc[g].w += ri * ae[g].w;
        }
    }
    float4* P4 = reinterpret_cast<float4*>(partial);
    #pragma unroll
    for (int g = 0; g < GROUPS; ++g)
        P4[(size_t)blockIdx.x * NF4 + g * THREADS + t] = acc[g];
}

// partial[nblocks][NN] -> partial2[16][NN]
__global__ __launch_bounds__(THREADS) void k_red1(const float* __restrict__ partial,
                                                  float* __restrict__ partial2,
                                                  int slices_per) {
    const int j4 = blockIdx.x * THREADS + threadIdx.x;
    const int s0 = blockIdx.y * slices_per;
    const float4* P4 = reinterpret_cast<const float4*>(partial);
    float4 acc = make_float4(0.f, 0.f, 0.f, 0.f);
    for (int s = s0; s < s0 + slices_per; ++s) {
        float4 v = P4[(size_t)s * NF4 + j4];
        acc.x += v.x; acc.y += v.y; acc.z += v.z; acc.w += v.w;
    }
    reinterpret_cast<float4*>(partial2)[(size_t)blockIdx.y * NF4 + j4] = acc;
}

// partial2[16][NN] -> c[j] = 1/sum
__global__ __launch_bounds__(THREADS) void k_red2(const float* __restrict__ partial2,
                                                  float* __restrict__ c) {
    const int j4 = blockIdx.x * THREADS + threadIdx.x;
    const float4* P4 = reinterpret_cast<const float4*>(partial2);
    float4 acc = make_float4(0.f, 0.f, 0.f, 0.f);
    for (int s = 0; s < 16; ++s) {
        float4 v = P4[(size_t)s * NF4 + j4];
        acc.x += v.x; acc.y += v.y; acc.z += v.z; acc.w += v.w;
    }
    float4 o = make_float4(1.f / acc.x, 1.f / acc.y, 1.f / acc.z, 1.f / acc.w);
    reinterpret_cast<float4*>(c)[j4] = o;
}

// out_ij = (A_ij+EPS) * r_i * c_j  (reversed block order: serpentine vs pass 5)
__global__ __launch_bounds__(THREADS) void k_finalize(const float* __restrict__ A,
                                                      const float* __restrict__ r,
                                                      const float* __restrict__ c,
                                                      float* __restrict__ out) {
    const float4* A4 = reinterpret_cast<const float4*>(A);
    const float4* c4 = reinterpret_cast<const float4*>(c);
    float4* O4 = reinterpret_cast<float4*>(out);
    const size_t total = (size_t)NN * NN / 4;
    const size_t stride = (size_t)gridDim.x * THREADS;
    const int rb = gridDim.x - 1 - blockIdx.x;
    for (size_t k = (size_t)rb * THREADS + threadIdx.x; k < total; k += stride) {
        const int row = (int)(k >> 11);       // NF4 == 2048
        const int jc = (int)(k & 2047);
        const float s = r[row];
        float4 a = A4[k];
        float4 w = c4[jc];
        float4 o;
        o.x = (a.x + EPS) * s * w.x;
        o.y = (a.y + EPS) * s * w.y;
        o.z = (a.z + EPS) * s * w.z;
        o.w = (a.w + EPS) * s * w.w;
        O4[k] = o;
    }
}

extern "C" void kernel_launch(void* const* d_in, const int* in_sizes, int n_in,
                              void* d_out, int out_size, void* d_ws, size_t ws_size,
                              hipStream_t stream) {
    const float* A = (const float*)d_in[0];
    float* out = (float*)d_out;

    // ws layout: r[NN] | c[NN] | partial2[16*NN] | partial[nblocks*NN]
    float* r = (float*)d_ws;
    float* c = r + NN;
    float* partial2 = c + NN;
    float* partial = partial2 + 16 * NN;

    int nblocks = 1024;
    while (nblocks > 16 &&
           (size_t)(2 + 16 + nblocks) * NN * sizeof(float) > ws_size)
        nblocks >>= 1;
    const int rows_per = NN / nblocks;
    const int slices_per = nblocks / 16;
    const dim3 g1(NF4 / THREADS, 16);

    // pass 0: c == ones
    k_pair<true, false><<<nblocks, THREADS, 0, stream>>>(A, c, r, partial, rows_per);
    k_red1<<<g1, THREADS, 0, stream>>>(partial, partial2, slices_per);
    k_red2<<<NF4 / THREADS, THREADS, 0, stream>>>(partial2, c);

    for (int p = 1; p < 5; ++p) {
        if (p & 1)
            k_pair<false, true><<<nblocks, THREADS, 0, stream>>>(A, c, r, partial, rows_per);
        else
            k_pair<false, false><<<nblocks, THREADS, 0, stream>>>(A, c, r, partial, rows_per);
        k_red1<<<g1, THREADS, 0, stream>>>(partial, partial2, slices_per);
        k_red2<<<NF4 / THREADS, THREADS, 0, stream>>>(partial2, c);
    }
    k_finalize<<<2048, THREADS, 0, stream>>>(A, r, c, out);
}

// Round 3
// 301.240 us; speedup vs baseline: 2.1603x; 1.5570x over previous
//
#include <hip/hip_runtime.h>
#include <hip/hip_fp16.h>

#define NN 8192
#define THREADS 256
#define NBLK 512
#define ROWS_PER (NN / NBLK)   // 16
#define RED1_OUT 32
constexpr float EPS = 1e-4f;

typedef float        f32x4 __attribute__((ext_vector_type(4)));
typedef unsigned int u32x4 __attribute__((ext_vector_type(4)));
typedef unsigned int u32x2 __attribute__((ext_vector_type(2)));

__device__ __forceinline__ float2 h2f2(unsigned int u) {
    __half2 h = __builtin_bit_cast(__half2, u);
    return __half22float2(h);
}
__device__ __forceinline__ unsigned int f2h2(float a, float b) {
    __half2 h = __floats2half2_rn(a, b);
    return __builtin_bit_cast(unsigned int, h);
}

// ---------------------------------------------------------------------------
// out_ij = (A_ij+EPS)*r_i*c_j. Pair pass p: r_i = 1/((A+e)_i . c); then
// partial col sums += r_i*(A+e)_ij. H = fp16(A+EPS) written once in pass 0;
// passes 1-4 + finalize read H (half traffic, IC-resident candidate).
// ---------------------------------------------------------------------------

// fp32-input pair pass. WH: also emit fp16 copy H. FIRST: c == ones.
template <bool FIRST, bool REV, bool WH>
__global__ __launch_bounds__(THREADS, 2)
void k_pair_f(const float* __restrict__ A, __half* __restrict__ H,
              const float* __restrict__ c, float* __restrict__ r_out,
              float* __restrict__ partial, int rows_per) {
    const int t = threadIdx.x;
    const f32x4* A4 = reinterpret_cast<const f32x4*>(A);
    const f32x4* c4 = reinterpret_cast<const f32x4*>(c);
    f32x4 creg[8];
    if (!FIRST) {
        #pragma unroll
        for (int g = 0; g < 8; ++g) creg[g] = c4[g * THREADS + t];
    }
    float acc[8][4];
    #pragma unroll
    for (int g = 0; g < 8; ++g)
        #pragma unroll
        for (int k = 0; k < 4; ++k) acc[g][k] = 0.f;

    __shared__ float smem[2][4][2];
    const int lane = t & 63, wid = t >> 6;
    const int base = REV ? NN - (blockIdx.x + 1) * rows_per
                         : blockIdx.x * rows_per;

    for (int rr = 0; rr < rows_per; rr += 2) {
        const size_t i0 = (size_t)(base + rr) * 2048;
        const size_t i1 = i0 + 2048;
        f32x4 e0[8], e1[8];
        #pragma unroll
        for (int g = 0; g < 8; ++g) {
            f32x4 a0 = WH ? __builtin_nontemporal_load(A4 + i0 + g * THREADS + t)
                          : A4[i0 + g * THREADS + t];
            f32x4 a1 = WH ? __builtin_nontemporal_load(A4 + i1 + g * THREADS + t)
                          : A4[i1 + g * THREADS + t];
            e0[g] = a0 + EPS;
            e1[g] = a1 + EPS;
        }
        float p0 = 0.f, p1 = 0.f;
        #pragma unroll
        for (int g = 0; g < 8; ++g) {
            if (FIRST) {
                p0 += e0[g].x + e0[g].y + e0[g].z + e0[g].w;
                p1 += e1[g].x + e1[g].y + e1[g].z + e1[g].w;
            } else {
                p0 += e0[g].x * creg[g].x + e0[g].y * creg[g].y
                    + e0[g].z * creg[g].z + e0[g].w * creg[g].w;
                p1 += e1[g].x * creg[g].x + e1[g].y * creg[g].y
                    + e1[g].z * creg[g].z + e1[g].w * creg[g].w;
            }
        }
        #pragma unroll
        for (int off = 32; off > 0; off >>= 1) {
            p0 += __shfl_down(p0, off);
            p1 += __shfl_down(p1, off);
        }
        const int buf = (rr >> 1) & 1;
        if (lane == 0) { smem[buf][wid][0] = p0; smem[buf][wid][1] = p1; }
        __syncthreads();
        const float ri0 = 1.f / (smem[buf][0][0] + smem[buf][1][0] +
                                 smem[buf][2][0] + smem[buf][3][0]);
        const float ri1 = 1.f / (smem[buf][0][1] + smem[buf][1][1] +
                                 smem[buf][2][1] + smem[buf][3][1]);
        if (t == 0) { r_out[base + rr] = ri0; r_out[base + rr + 1] = ri1; }
        if (WH) {
            u32x2* H2 = reinterpret_cast<u32x2*>(H);
            #pragma unroll
            for (int g = 0; g < 8; ++g) {
                u32x2 w0, w1;
                w0.x = f2h2(e0[g].x, e0[g].y); w0.y = f2h2(e0[g].z, e0[g].w);
                w1.x = f2h2(e1[g].x, e1[g].y); w1.y = f2h2(e1[g].z, e1[g].w);
                H2[i0 + g * THREADS + t] = w0;
                H2[i1 + g * THREADS + t] = w1;
            }
        }
        #pragma unroll
        for (int g = 0; g < 8; ++g) {
            acc[g][0] += ri0 * e0[g].x + ri1 * e1[g].x;
            acc[g][1] += ri0 * e0[g].y + ri1 * e1[g].y;
            acc[g][2] += ri0 * e0[g].z + ri1 * e1[g].z;
            acc[g][3] += ri0 * e0[g].w + ri1 * e1[g].w;
        }
    }
    f32x4* P4 = reinterpret_cast<f32x4*>(partial);
    #pragma unroll
    for (int g = 0; g < 8; ++g) {
        f32x4 v; v.x = acc[g][0]; v.y = acc[g][1]; v.z = acc[g][2]; v.w = acc[g][3];
        P4[(size_t)blockIdx.x * 2048 + g * THREADS + t] = v;
    }
}

// fp16-input pair pass (passes 1-4 of the H path).
template <bool REV>
__global__ __launch_bounds__(THREADS, 2)
void k_pair_h(const __half* __restrict__ H, const float* __restrict__ c,
              float* __restrict__ r_out, float* __restrict__ partial) {
    const int t = threadIdx.x;
    const u32x4* H4 = reinterpret_cast<const u32x4*>(H);
    const f32x4* c4 = reinterpret_cast<const f32x4*>(c);
    f32x4 creg[4][2];
    #pragma unroll
    for (int g = 0; g < 4; ++g) {
        creg[g][0] = c4[(g * THREADS + t) * 2];
        creg[g][1] = c4[(g * THREADS + t) * 2 + 1];
    }
    float acc[4][8];
    #pragma unroll
    for (int g = 0; g < 4; ++g)
        #pragma unroll
        for (int k = 0; k < 8; ++k) acc[g][k] = 0.f;

    __shared__ float smem[2][4][2];
    const int lane = t & 63, wid = t >> 6;
    const int base = REV ? NN - (blockIdx.x + 1) * ROWS_PER
                         : blockIdx.x * ROWS_PER;

    for (int rr = 0; rr < ROWS_PER; rr += 2) {
        const size_t i0 = (size_t)(base + rr) * 1024;
        const size_t i1 = i0 + 1024;
        u32x4 q0[4], q1[4];
        #pragma unroll
        for (int g = 0; g < 4; ++g) {
            q0[g] = H4[i0 + g * THREADS + t];
            q1[g] = H4[i1 + g * THREADS + t];
        }
        float p0 = 0.f, p1 = 0.f;
        #pragma unroll
        for (int g = 0; g < 4; ++g) {
            float2 f;
            f = h2f2(q0[g].x); p0 += f.x * creg[g][0].x + f.y * creg[g][0].y;
            f = h2f2(q0[g].y); p0 += f.x * creg[g][0].z + f.y * creg[g][0].w;
            f = h2f2(q0[g].z); p0 += f.x * creg[g][1].x + f.y * creg[g][1].y;
            f = h2f2(q0[g].w); p0 += f.x * creg[g][1].z + f.y * creg[g][1].w;
            f = h2f2(q1[g].x); p1 += f.x * creg[g][0].x + f.y * creg[g][0].y;
            f = h2f2(q1[g].y); p1 += f.x * creg[g][0].z + f.y * creg[g][0].w;
            f = h2f2(q1[g].z); p1 += f.x * creg[g][1].x + f.y * creg[g][1].y;
            f = h2f2(q1[g].w); p1 += f.x * creg[g][1].z + f.y * creg[g][1].w;
        }
        #pragma unroll
        for (int off = 32; off > 0; off >>= 1) {
            p0 += __shfl_down(p0, off);
            p1 += __shfl_down(p1, off);
        }
        const int buf = (rr >> 1) & 1;
        if (lane == 0) { smem[buf][wid][0] = p0; smem[buf][wid][1] = p1; }
        __syncthreads();
        const float ri0 = 1.f / (smem[buf][0][0] + smem[buf][1][0] +
                                 smem[buf][2][0] + smem[buf][3][0]);
        const float ri1 = 1.f / (smem[buf][0][1] + smem[buf][1][1] +
                                 smem[buf][2][1] + smem[buf][3][1]);
        if (t == 0) { r_out[base + rr] = ri0; r_out[base + rr + 1] = ri1; }
        #pragma unroll
        for (int g = 0; g < 4; ++g) {
            float2 f;
            f = h2f2(q0[g].x); acc[g][0] += ri0 * f.x; acc[g][1] += ri0 * f.y;
            f = h2f2(q0[g].y); acc[g][2] += ri0 * f.x; acc[g][3] += ri0 * f.y;
            f = h2f2(q0[g].z); acc[g][4] += ri0 * f.x; acc[g][5] += ri0 * f.y;
            f = h2f2(q0[g].w); acc[g][6] += ri0 * f.x; acc[g][7] += ri0 * f.y;
            f = h2f2(q1[g].x); acc[g][0] += ri1 * f.x; acc[g][1] += ri1 * f.y;
            f = h2f2(q1[g].y); acc[g][2] += ri1 * f.x; acc[g][3] += ri1 * f.y;
            f = h2f2(q1[g].z); acc[g][4] += ri1 * f.x; acc[g][5] += ri1 * f.y;
            f = h2f2(q1[g].w); acc[g][6] += ri1 * f.x; acc[g][7] += ri1 * f.y;
        }
    }
    f32x4* P4 = reinterpret_cast<f32x4*>(partial);
    #pragma unroll
    for (int g = 0; g < 4; ++g) {
        f32x4 v0, v1;
        v0.x = acc[g][0]; v0.y = acc[g][1]; v0.z = acc[g][2]; v0.w = acc[g][3];
        v1.x = acc[g][4]; v1.y = acc[g][5]; v1.z = acc[g][6]; v1.w = acc[g][7];
        P4[(size_t)blockIdx.x * 2048 + (g * THREADS + t) * 2]     = v0;
        P4[(size_t)blockIdx.x * 2048 + (g * THREADS + t) * 2 + 1] = v1;
    }
}

__global__ __launch_bounds__(THREADS, 4)
void k_red1(const float* __restrict__ partial, float* __restrict__ partial2,
            int slices_per) {
    const int j4 = blockIdx.x * THREADS + threadIdx.x;
    const int s0 = blockIdx.y * slices_per;
    const f32x4* P = reinterpret_cast<const f32x4*>(partial);
    f32x4 acc = {0.f, 0.f, 0.f, 0.f};
    for (int s = 0; s < slices_per; ++s) acc += P[(size_t)(s0 + s) * 2048 + j4];
    reinterpret_cast<f32x4*>(partial2)[(size_t)blockIdx.y * 2048 + j4] = acc;
}

__global__ __launch_bounds__(THREADS, 4)
void k_red2(const float* __restrict__ partial2, float* __restrict__ c) {
    const int j4 = blockIdx.x * THREADS + threadIdx.x;
    const f32x4* P = reinterpret_cast<const f32x4*>(partial2);
    f32x4 acc = {0.f, 0.f, 0.f, 0.f};
    #pragma unroll
    for (int s = 0; s < RED1_OUT; ++s) acc += P[(size_t)s * 2048 + j4];
    f32x4 o;
    o.x = 1.f / acc.x; o.y = 1.f / acc.y; o.z = 1.f / acc.z; o.w = 1.f / acc.w;
    reinterpret_cast<f32x4*>(c)[j4] = o;
}

__global__ __launch_bounds__(THREADS, 4)
void k_finalize_h(const __half* __restrict__ H, const float* __restrict__ r,
                  const float* __restrict__ c, float* __restrict__ out) {
    const u32x4* H4 = reinterpret_cast<const u32x4*>(H);
    const f32x4* c4 = reinterpret_cast<const f32x4*>(c);
    f32x4* O4 = reinterpret_cast<f32x4*>(out);
    const size_t total = (size_t)NN * 1024;
    const size_t stride = (size_t)gridDim.x * THREADS;
    const int rb = gridDim.x - 1 - blockIdx.x;
    for (size_t k = (size_t)rb * THREADS + threadIdx.x; k < total; k += stride) {
        const int row = (int)(k >> 10);
        const int u = (int)(k & 1023);
        u32x4 q = H4[k];
        f32x4 cc0 = c4[u * 2], cc1 = c4[u * 2 + 1];
        const float rv = r[row];
        float2 f;
        f32x4 o0, o1;
        f = h2f2(q.x); o0.x = f.x * rv * cc0.x; o0.y = f.y * rv * cc0.y;
        f = h2f2(q.y); o0.z = f.x * rv * cc0.z; o0.w = f.y * rv * cc0.w;
        f = h2f2(q.z); o1.x = f.x * rv * cc1.x; o1.y = f.y * rv * cc1.y;
        f = h2f2(q.w); o1.z = f.x * rv * cc1.z; o1.w = f.y * rv * cc1.w;
        __builtin_nontemporal_store(o0, O4 + (size_t)row * 2048 + u * 2);
        __builtin_nontemporal_store(o1, O4 + (size_t)row * 2048 + u * 2 + 1);
    }
}

__global__ __launch_bounds__(THREADS, 4)
void k_finalize_f(const float* __restrict__ A, const float* __restrict__ r,
                  const float* __restrict__ c, float* __restrict__ out) {
    const f32x4* A4 = reinterpret_cast<const f32x4*>(A);
    const f32x4* c4 = reinterpret_cast<const f32x4*>(c);
    f32x4* O4 = reinterpret_cast<f32x4*>(out);
    const size_t total = (size_t)NN * 2048;
    const size_t stride = (size_t)gridDim.x * THREADS;
    const int rb = gridDim.x - 1 - blockIdx.x;
    for (size_t k = (size_t)rb * THREADS + threadIdx.x; k < total; k += stride) {
        const int row = (int)(k >> 11);
        const int jc = (int)(k & 2047);
        const float s = r[row];
        f32x4 a = A4[k];
        f32x4 w = c4[jc];
        f32x4 o;
        o.x = (a.x + EPS) * s * w.x;
        o.y = (a.y + EPS) * s * w.y;
        o.z = (a.z + EPS) * s * w.z;
        o.w = (a.w + EPS) * s * w.w;
        __builtin_nontemporal_store(o, O4 + k);
    }
}

extern "C" void kernel_launch(void* const* d_in, const int* in_sizes, int n_in,
                              void* d_out, int out_size, void* d_ws, size_t ws_size,
                              hipStream_t stream) {
    (void)in_sizes; (void)n_in; (void)out_size;
    const float* A = (const float*)d_in[0];
    float* out = (float*)d_out;

    const size_t h_bytes = (size_t)NN * NN * sizeof(__half);        // 128 MB
    const size_t small_f = (size_t)(2 * NN + RED1_OUT * NN);        // r,c,partial2
    const size_t part_f  = (size_t)NBLK * NN;

    if (ws_size >= h_bytes + (small_f + part_f) * sizeof(float)) {
        // ---- fp16 working-copy path ----
        char* p = (char*)d_ws;
        __half* H = (__half*)p;            p += h_bytes;
        float* r = (float*)p;              p += NN * sizeof(float);
        float* c = (float*)p;              p += NN * sizeof(float);
        float* partial2 = (float*)p;       p += (size_t)RED1_OUT * NN * sizeof(float);
        float* partial = (float*)p;

        const dim3 g1(8, RED1_OUT);
        k_pair_f<true, false, true><<<NBLK, THREADS, 0, stream>>>(A, H, nullptr, r,
                                                                  partial, ROWS_PER);
        k_red1<<<g1, THREADS, 0, stream>>>(partial, partial2, NBLK / RED1_OUT);
        k_red2<<<8, THREADS, 0, stream>>>(partial2, c);
        for (int ppass = 1; ppass < 5; ++ppass) {
            if (ppass & 1)
                k_pair_h<true><<<NBLK, THREADS, 0, stream>>>(H, c, r, partial);
            else
                k_pair_h<false><<<NBLK, THREADS, 0, stream>>>(H, c, r, partial);
            k_red1<<<g1, THREADS, 0, stream>>>(partial, partial2, NBLK / RED1_OUT);
            k_red2<<<8, THREADS, 0, stream>>>(partial2, c);
        }
        k_finalize_h<<<2048, THREADS, 0, stream>>>(H, r, c, out);
    } else {
        // ---- fp32 fallback (ws too small for H) ----
        int nblocks = NBLK;
        while (nblocks > RED1_OUT &&
               (small_f + (size_t)nblocks * NN) * sizeof(float) > ws_size)
            nblocks >>= 1;
        const int rows_per = NN / nblocks;
        float* r = (float*)d_ws;
        float* c = r + NN;
        float* partial2 = c + NN;
        float* partial = partial2 + (size_t)RED1_OUT * NN;
        const dim3 g1(8, RED1_OUT);

        k_pair_f<true, false, false><<<nblocks, THREADS, 0, stream>>>(A, nullptr,
                                                                      nullptr, r,
                                                                      partial, rows_per);
        k_red1<<<g1, THREADS, 0, stream>>>(partial, partial2, nblocks / RED1_OUT);
        k_red2<<<8, THREADS, 0, stream>>>(partial2, c);
        for (int ppass = 1; ppass < 5; ++ppass) {
            if (ppass & 1)
                k_pair_f<false, true, false><<<nblocks, THREADS, 0, stream>>>(
                    A, nullptr, c, r, partial, rows_per);
            else
                k_pair_f<false, false, false><<<nblocks, THREADS, 0, stream>>>(
                    A, nullptr, c, r, partial, rows_per);
            k_red1<<<g1, THREADS, 0, stream>>>(partial, partial2, nblocks / RED1_OUT);
            k_red2<<<8, THREADS, 0, stream>>>(partial2, c);
        }
        k_finalize_f<<<2048, THREADS, 0, stream>>>(A, r, c, out);
    }
}

// Round 5
// 262.127 us; speedup vs baseline: 2.4826x; 1.1492x over previous
//
#include <hip/hip_runtime.h>

#define NN 8192
#define NF4 2048              // f32x4 (and u32) per row
#define NQ4 512               // u32x4 (16 fp8) per row
#define THREADS 256
#define NBLK 512
#define RPB 16                // rows per pair block
#define RED1_OUT 32
#define SLICES_PER (NBLK / RED1_OUT)   // 16

constexpr float EPS = 1e-4f;
constexpr float QSCALE = 16.0f;  // power of 2: cancels exactly in r*c

typedef float        f32x4 __attribute__((ext_vector_type(4)));
typedef unsigned int u32x4 __attribute__((ext_vector_type(4)));

// ---------------------------------------------------------------------------
// out_ij = (A_ij+EPS)*r_i*c_j. Pair pass p: r_i = 1/((A+e)_i . c); partial
// col sums += r_i*(A+e)_ij. Pass 0 reads fp32 A once and emits Q = fp8_e4m3
// (QSCALE*(A+EPS)); passes 1-4 read Q (64 MB, IC-resident candidate);
// finalize reads fp32 A again (exact epilogue, no quantization error).
// Partial layout is slot-permuted (slot = w*512+u for true f32x4 idx u*4+w)
// so pair-kernel partial stores are coalesced; red2 un-permutes into c.
// ---------------------------------------------------------------------------

__device__ __forceinline__ unsigned int pack4(f32x4 v) {
    int r = 0;
    r = __builtin_amdgcn_cvt_pk_fp8_f32(v.x, v.y, r, false);  // bytes 0-1
    r = __builtin_amdgcn_cvt_pk_fp8_f32(v.z, v.w, r, true);   // bytes 2-3
    return (unsigned int)r;
}

__device__ __forceinline__ f32x4 unpack4(unsigned int u) {
    auto lo = __builtin_amdgcn_cvt_pk_f32_fp8(u, false);  // native float2 vec
    auto hi = __builtin_amdgcn_cvt_pk_f32_fp8(u, true);
    f32x4 r;
    r.x = lo[0]; r.y = lo[1]; r.z = hi[0]; r.w = hi[1];
    return r;
}

// fp32-A pair pass. FIRST: c==ones. WQ: emit fp8 working copy Q.
template <bool FIRST, bool REV, bool WQ>
__global__ __launch_bounds__(THREADS, 2)
void k_pair_a(const float* __restrict__ A, unsigned int* __restrict__ Q,
              const float* __restrict__ c, float* __restrict__ r_out,
              float* __restrict__ partial) {
    const int t = threadIdx.x;
    const f32x4* A4 = reinterpret_cast<const f32x4*>(A);
    f32x4 creg[8];
    if constexpr (!FIRST) {
        const f32x4* c4 = reinterpret_cast<const f32x4*>(c);
        #pragma unroll
        for (int g = 0; g < 8; ++g) creg[g] = c4[g * THREADS + t];
    }
    float acc[8][4];
    #pragma unroll
    for (int g = 0; g < 8; ++g)
        #pragma unroll
        for (int k = 0; k < 4; ++k) acc[g][k] = 0.f;

    __shared__ float smem[2][4][2];
    __shared__ float lbuf[NN];   // 32 KB: slot-reorder staging for partial
    const int lane = t & 63, wid = t >> 6;
    const int base = REV ? NN - (blockIdx.x + 1) * RPB : blockIdx.x * RPB;

    for (int rr = 0; rr < RPB; rr += 2) {
        const size_t i0 = (size_t)(base + rr) * NF4;
        const size_t i1 = i0 + NF4;
        f32x4 e0[8], e1[8];
        #pragma unroll
        for (int g = 0; g < 8; ++g) {
            e0[g] = __builtin_nontemporal_load(A4 + i0 + g * THREADS + t) + EPS;
            e1[g] = __builtin_nontemporal_load(A4 + i1 + g * THREADS + t) + EPS;
        }
        float p0 = 0.f, p1 = 0.f;
        #pragma unroll
        for (int g = 0; g < 8; ++g) {
            if constexpr (FIRST) {
                p0 += e0[g].x + e0[g].y + e0[g].z + e0[g].w;
                p1 += e1[g].x + e1[g].y + e1[g].z + e1[g].w;
            } else {
                p0 += e0[g].x * creg[g].x + e0[g].y * creg[g].y
                    + e0[g].z * creg[g].z + e0[g].w * creg[g].w;
                p1 += e1[g].x * creg[g].x + e1[g].y * creg[g].y
                    + e1[g].z * creg[g].z + e1[g].w * creg[g].w;
            }
        }
        #pragma unroll
        for (int off = 32; off > 0; off >>= 1) {
            p0 += __shfl_down(p0, off);
            p1 += __shfl_down(p1, off);
        }
        const int buf = (rr >> 1) & 1;
        if (lane == 0) { smem[buf][wid][0] = p0; smem[buf][wid][1] = p1; }
        __syncthreads();
        const float ri0 = 1.f / (smem[buf][0][0] + smem[buf][1][0] +
                                 smem[buf][2][0] + smem[buf][3][0]);
        const float ri1 = 1.f / (smem[buf][0][1] + smem[buf][1][1] +
                                 smem[buf][2][1] + smem[buf][3][1]);
        if (t == 0) { r_out[base + rr] = ri0; r_out[base + rr + 1] = ri1; }
        if constexpr (WQ) {
            #pragma unroll
            for (int g = 0; g < 8; ++g) {
                Q[i0 + g * THREADS + t] = pack4(e0[g] * QSCALE);
                Q[i1 + g * THREADS + t] = pack4(e1[g] * QSCALE);
            }
        }
        #pragma unroll
        for (int g = 0; g < 8; ++g) {
            acc[g][0] += ri0 * e0[g].x + ri1 * e1[g].x;
            acc[g][1] += ri0 * e0[g].y + ri1 * e1[g].y;
            acc[g][2] += ri0 * e0[g].z + ri1 * e1[g].z;
            acc[g][3] += ri0 * e0[g].w + ri1 * e1[g].w;
        }
    }
    // restage through LDS so global partial stores are slot-ordered/coalesced
    f32x4* L4 = reinterpret_cast<f32x4*>(lbuf);
    #pragma unroll
    for (int g = 0; g < 8; ++g) {
        f32x4 v;
        v.x = acc[g][0]; v.y = acc[g][1]; v.z = acc[g][2]; v.w = acc[g][3];
        L4[g * THREADS + t] = v;
    }
    __syncthreads();
    f32x4* P4 = reinterpret_cast<f32x4*>(partial);
    #pragma unroll
    for (int g = 0; g < 2; ++g)
        #pragma unroll
        for (int w = 0; w < 4; ++w) {
            f32x4 v = L4[(g * THREADS + t) * 4 + w];
            P4[(size_t)blockIdx.x * NF4 + w * NQ4 + g * THREADS + t] = v;
        }
}

// fp8-Q pair pass (passes 1-4). ri is 1/QSCALE-scaled inside; cancels in acc.
template <bool REV>
__global__ __launch_bounds__(THREADS, 2)
void k_pair_q(const unsigned int* __restrict__ Q, const float* __restrict__ c,
              float* __restrict__ r_out, float* __restrict__ partial) {
    const int t = threadIdx.x;
    const u32x4* Q4 = reinterpret_cast<const u32x4*>(Q);
    const f32x4* c4 = reinterpret_cast<const f32x4*>(c);
    f32x4 creg[2][4];
    #pragma unroll
    for (int g = 0; g < 2; ++g)
        #pragma unroll
        for (int j = 0; j < 4; ++j)
            creg[g][j] = c4[(size_t)(g * THREADS + t) * 4 + j];
    float acc[2][16];
    #pragma unroll
    for (int g = 0; g < 2; ++g)
        #pragma unroll
        for (int k = 0; k < 16; ++k) acc[g][k] = 0.f;

    __shared__ float smem[2][4][2];
    const int lane = t & 63, wid = t >> 6;
    const int base = REV ? NN - (blockIdx.x + 1) * RPB : blockIdx.x * RPB;

    for (int rr = 0; rr < RPB; rr += 2) {
        const size_t i0 = (size_t)(base + rr) * NQ4;
        const size_t i1 = i0 + NQ4;
        u32x4 q0[2], q1[2];
        #pragma unroll
        for (int g = 0; g < 2; ++g) {
            q0[g] = Q4[i0 + g * THREADS + t];
            q1[g] = Q4[i1 + g * THREADS + t];
        }
        float p0 = 0.f, p1 = 0.f;
        #pragma unroll
        for (int g = 0; g < 2; ++g)
            #pragma unroll
            for (int w = 0; w < 4; ++w) {
                f32x4 v0 = unpack4(q0[g][w]);
                f32x4 v1 = unpack4(q1[g][w]);
                p0 += v0.x * creg[g][w].x + v0.y * creg[g][w].y
                    + v0.z * creg[g][w].z + v0.w * creg[g][w].w;
                p1 += v1.x * creg[g][w].x + v1.y * creg[g][w].y
                    + v1.z * creg[g][w].z + v1.w * creg[g][w].w;
            }
        #pragma unroll
        for (int off = 32; off > 0; off >>= 1) {
            p0 += __shfl_down(p0, off);
            p1 += __shfl_down(p1, off);
        }
        const int buf = (rr >> 1) & 1;
        if (lane == 0) { smem[buf][wid][0] = p0; smem[buf][wid][1] = p1; }
        __syncthreads();
        const float ri0 = 1.f / (smem[buf][0][0] + smem[buf][1][0] +
                                 smem[buf][2][0] + smem[buf][3][0]);
        const float ri1 = 1.f / (smem[buf][0][1] + smem[buf][1][1] +
                                 smem[buf][2][1] + smem[buf][3][1]);
        if (t == 0) {
            r_out[base + rr]     = ri0 * QSCALE;   // true-scale r
            r_out[base + rr + 1] = ri1 * QSCALE;
        }
        #pragma unroll
        for (int g = 0; g < 2; ++g)
            #pragma unroll
            for (int w = 0; w < 4; ++w) {
                f32x4 v0 = unpack4(q0[g][w]);
                f32x4 v1 = unpack4(q1[g][w]);
                acc[g][w * 4 + 0] += ri0 * v0.x + ri1 * v1.x;
                acc[g][w * 4 + 1] += ri0 * v0.y + ri1 * v1.y;
                acc[g][w * 4 + 2] += ri0 * v0.z + ri1 * v1.z;
                acc[g][w * 4 + 3] += ri0 * v0.w + ri1 * v1.w;
            }
    }
    f32x4* P4 = reinterpret_cast<f32x4*>(partial);
    #pragma unroll
    for (int g = 0; g < 2; ++g)
        #pragma unroll
        for (int w = 0; w < 4; ++w) {
            f32x4 v;
            v.x = acc[g][w * 4 + 0]; v.y = acc[g][w * 4 + 1];
            v.z = acc[g][w * 4 + 2]; v.w = acc[g][w * 4 + 3];
            P4[(size_t)blockIdx.x * NF4 + w * NQ4 + g * THREADS + t] = v;
        }
}

__global__ __launch_bounds__(THREADS, 4)
void k_red1(const float* __restrict__ partial, float* __restrict__ partial2) {
    const int j4 = blockIdx.x * THREADS + threadIdx.x;   // storage slot
    const int s0 = blockIdx.y * SLICES_PER;
    const f32x4* P = reinterpret_cast<const f32x4*>(partial);
    f32x4 acc = {0.f, 0.f, 0.f, 0.f};
    #pragma unroll 4
    for (int s = 0; s < SLICES_PER; ++s) acc += P[(size_t)(s0 + s) * NF4 + j4];
    reinterpret_cast<f32x4*>(partial2)[(size_t)blockIdx.y * NF4 + j4] = acc;
}

__global__ __launch_bounds__(THREADS, 4)
void k_red2(const float* __restrict__ partial2, float* __restrict__ c) {
    const int j4 = blockIdx.x * THREADS + threadIdx.x;   // storage slot
    const f32x4* P = reinterpret_cast<const f32x4*>(partial2);
    f32x4 acc = {0.f, 0.f, 0.f, 0.f};
    #pragma unroll
    for (int s = 0; s < RED1_OUT; ++s) acc += P[(size_t)s * NF4 + j4];
    f32x4 o;
    o.x = 1.f / acc.x; o.y = 1.f / acc.y; o.z = 1.f / acc.z; o.w = 1.f / acc.w;
    const int w = j4 >> 9, u = j4 & 511;                 // un-permute slot
    reinterpret_cast<f32x4*>(c)[u * 4 + w] = o;
}

// exact fp32 epilogue from A
__global__ __launch_bounds__(THREADS, 4)
void k_finalize(const float* __restrict__ A, const float* __restrict__ r,
                const float* __restrict__ c, float* __restrict__ out) {
    const f32x4* A4 = reinterpret_cast<const f32x4*>(A);
    const f32x4* c4 = reinterpret_cast<const f32x4*>(c);
    f32x4* O4 = reinterpret_cast<f32x4*>(out);
    const size_t total = (size_t)NN * NF4;
    const size_t stride = (size_t)gridDim.x * THREADS;
    for (size_t k = (size_t)blockIdx.x * THREADS + threadIdx.x; k < total;
         k += stride) {
        const int row = (int)(k >> 11);
        const int jc = (int)(k & 2047);
        f32x4 a = __builtin_nontemporal_load(A4 + k);
        f32x4 w = c4[jc];
        const float s = r[row];
        f32x4 o = (a + EPS) * (s * w);
        __builtin_nontemporal_store(o, O4 + k);
    }
}

extern "C" void kernel_launch(void* const* d_in, const int* in_sizes, int n_in,
                              void* d_out, int out_size, void* d_ws, size_t ws_size,
                              hipStream_t stream) {
    (void)in_sizes; (void)n_in; (void)out_size;
    const float* A = (const float*)d_in[0];
    float* out = (float*)d_out;
    const dim3 g1(NF4 / THREADS, RED1_OUT);   // (8, 32)

    const size_t q_bytes = (size_t)NN * NN;   // 64 MB
    const size_t small_b = (size_t)(2 * NN + RED1_OUT * NN + NBLK * NN) * sizeof(float);

    if (ws_size >= q_bytes + small_b) {
        char* p = (char*)d_ws;
        unsigned int* Q = (unsigned int*)p;  p += q_bytes;
        float* r = (float*)p;                p += NN * sizeof(float);
        float* c = (float*)p;                p += NN * sizeof(float);
        float* partial2 = (float*)p;         p += (size_t)RED1_OUT * NN * sizeof(float);
        float* partial = (float*)p;

        k_pair_a<true, false, true><<<NBLK, THREADS, 0, stream>>>(A, Q, nullptr, r, partial);
        k_red1<<<g1, THREADS, 0, stream>>>(partial, partial2);
        k_red2<<<NF4 / THREADS, THREADS, 0, stream>>>(partial2, c);

        k_pair_q<true><<<NBLK, THREADS, 0, stream>>>(Q, c, r, partial);
        k_red1<<<g1, THREADS, 0, stream>>>(partial, partial2);
        k_red2<<<NF4 / THREADS, THREADS, 0, stream>>>(partial2, c);

        k_pair_q<false><<<NBLK, THREADS, 0, stream>>>(Q, c, r, partial);
        k_red1<<<g1, THREADS, 0, stream>>>(partial, partial2);
        k_red2<<<NF4 / THREADS, THREADS, 0, stream>>>(partial2, c);

        k_pair_q<true><<<NBLK, THREADS, 0, stream>>>(Q, c, r, partial);
        k_red1<<<g1, THREADS, 0, stream>>>(partial, partial2);
        k_red2<<<NF4 / THREADS, THREADS, 0, stream>>>(partial2, c);

        k_pair_q<false><<<NBLK, THREADS, 0, stream>>>(Q, c, r, partial);
        k_red1<<<g1, THREADS, 0, stream>>>(partial, partial2);
        k_red2<<<NF4 / THREADS, THREADS, 0, stream>>>(partial2, c);

        k_finalize<<<2048, THREADS, 0, stream>>>(A, r, c, out);
    } else {
        // fp32 fallback: all passes read A directly
        float* r = (float*)d_ws;
        float* c = r + NN;
        float* partial2 = c + NN;
        float* partial = partial2 + (size_t)RED1_OUT * NN;

        k_pair_a<true, false, false><<<NBLK, THREADS, 0, stream>>>(A, nullptr, nullptr, r, partial);
        k_red1<<<g1, THREADS, 0, stream>>>(partial, partial2);
        k_red2<<<NF4 / THREADS, THREADS, 0, stream>>>(partial2, c);

        k_pair_a<false, true, false><<<NBLK, THREADS, 0, stream>>>(A, nullptr, c, r, partial);
        k_red1<<<g1, THREADS, 0, stream>>>(partial, partial2);
        k_red2<<<NF4 / THREADS, THREADS, 0, stream>>>(partial2, c);

        k_pair_a<false, false, false><<<NBLK, THREADS, 0, stream>>>(A, nullptr, c, r, partial);
        k_red1<<<g1, THREADS, 0, stream>>>(partial, partial2);
        k_red2<<<NF4 / THREADS, THREADS, 0, stream>>>(partial2, c);

        k_pair_a<false, true, false><<<NBLK, THREADS, 0, stream>>>(A, nullptr, c, r, partial);
        k_red1<<<g1, THREADS, 0, stream>>>(partial, partial2);
        k_red2<<<NF4 / THREADS, THREADS, 0, stream>>>(partial2, c);

        k_pair_a<false, false, false><<<NBLK, THREADS, 0, stream>>>(A, nullptr, c, r, partial);
        k_red1<<<g1, THREADS, 0, stream>>>(partial, partial2);
        k_red2<<<NF4 / THREADS, THREADS, 0, stream>>>(partial2, c);

        k_finalize<<<2048, THREADS, 0, stream>>>(A, r, c, out);
    }
}